// Round 11
// baseline (6825.920 us; speedup 1.0000x reference)
//
#include <hip/hip_runtime.h>
#include <stdint.h>
#include <math.h>

#define NB 512
#define NS 200
#define NH 128
#define NH3 384
#define NT 1024
#define NWAVE 16

// ---------------- XLA-exact scalar helpers (GRU gate path only) ----------------
__device__ __forceinline__ float xla_tanhf(float x) {
  float cx = fminf(fmaxf(x, -9.0f), 9.0f);
  float x2 = __fmul_rn(cx, cx);
  float p = -2.76076847742355e-16f;
  p = __fadd_rn(__fmul_rn(x2, p), 2.00018790482477e-13f);
  p = __fadd_rn(__fmul_rn(x2, p), -8.60467152213735e-11f);
  p = __fadd_rn(__fmul_rn(x2, p), 5.12229709037114e-08f);
  p = __fadd_rn(__fmul_rn(x2, p), 1.48572235717979e-05f);
  p = __fadd_rn(__fmul_rn(x2, p), 6.37261928875436e-04f);
  p = __fadd_rn(__fmul_rn(x2, p), 4.89352455891786e-03f);
  p = __fmul_rn(cx, p);
  float q = 1.19825839466702e-06f;
  q = __fadd_rn(__fmul_rn(x2, q), 1.18534705686654e-04f);
  q = __fadd_rn(__fmul_rn(x2, q), 2.26843463243900e-03f);
  q = __fadd_rn(__fmul_rn(x2, q), 4.89352518554385e-03f);
  float r = __fdiv_rn(p, q);
  return (fabsf(x) < 0.0004f) ? x : r;
}

__device__ __forceinline__ float xla_sigmoidf(float x) {
  return __fadd_rn(0.5f, __fmul_rn(0.5f, xla_tanhf(__fmul_rn(0.5f, x))));
}

// exp-based fast tanh for logit paths — validated r10 (absmax 0.0)
__device__ __forceinline__ float fast_tanhf(float x) {
  float e = __expf(__fmul_rn(x, 2.0f));
  float r = __builtin_amdgcn_rcpf(__fadd_rn(e, 1.0f));
  return fmaf(-2.0f, r, 1.0f);
}

__device__ __forceinline__ uint32_t rotl32(uint32_t v, int r) {
  return (v << r) | (v >> (32 - r));
}
__device__ __forceinline__ void threefry2x32(uint32_t k0, uint32_t k1,
                                             uint32_t x0, uint32_t x1,
                                             uint32_t& o0, uint32_t& o1) {
  uint32_t k2 = k0 ^ k1 ^ 0x1BD11BDAu;
  x0 += k0; x1 += k1;
  #define TFR(r) { x0 += x1; x1 = rotl32(x1, r); x1 ^= x0; }
  TFR(13) TFR(15) TFR(26) TFR(6)
  x0 += k1; x1 += k2 + 1u;
  TFR(17) TFR(29) TFR(16) TFR(24)
  x0 += k2; x1 += k0 + 2u;
  TFR(13) TFR(15) TFR(26) TFR(6)
  x0 += k0; x1 += k1 + 3u;
  TFR(17) TFR(29) TFR(16) TFR(24)
  x0 += k1; x1 += k2 + 4u;
  TFR(13) TFR(15) TFR(26) TFR(6)
  x0 += k2; x1 += k0 + 5u;
  #undef TFR
  o0 = x0; o1 = x1;
}

__device__ __forceinline__ float bits_to_gumbel(uint32_t bits) {
  const float kTiny = 1.1754943508222875e-38f;
  float f = __fsub_rn(__uint_as_float((bits >> 9) | 0x3F800000u), 1.0f);
  float u = __fadd_rn(__fmul_rn(f, __fsub_rn(1.0f, kTiny)), kTiny);
  u = fmaxf(kTiny, u);
  return -logf(-logf(u));
}

// ---------------- persistent kernel: 1 row/block, 1024 threads, 8 waves/SIMD --
// S1: t<768 -> one GRU dot each (bit-exact chains)
// S4/S5: t<800 -> s = t>>2 (0..199), q = t&3, h = q+4j (j<32)
__global__ __launch_bounds__(NT, 8) void k_decode(
    const float* __restrict__ stat, const float* __restrict__ dyn,
    const float* __restrict__ sW,   const float* __restrict__ sb,
    const float* __restrict__ dW,   const float* __restrict__ db,
    const float* __restrict__ x0,   const float* __restrict__ h0,
    const float* __restrict__ Wemb, const float* __restrict__ bemb,
    const float* __restrict__ Wih,  const float* __restrict__ Whh,
    const float* __restrict__ bih,  const float* __restrict__ bhh,
    const float* __restrict__ Wa,   const float* __restrict__ va,
    const float* __restrict__ Wd,   const float* __restrict__ vd,
    float* __restrict__ out) {

  __shared__ __align__(16) float st0L[NS], st1L[NS], dy0L[NS], dy1L[NS];
  __shared__ float4 AF4[NH];               // {As0,As1,Ad0,Ad1}
  __shared__ float4 DF4[NH];               // {Ds0,Ds1,vd, ct_full (per-step)}
  __shared__ float4 CW4[NH];               // {Cw0,Cw1,Cwb,Dc}
  __shared__ float2 HtVa[NH];              // {va, Ht+Ac (per-step)}
  __shared__ float  AcL[NH];
  __shared__ float WembL[2*NH], bembL[NH];
  __shared__ float bihL[NH3], bhhL[NH3];
  __shared__ __align__(16) float embL[NH], hL[NH];
  __shared__ float giL[NH3], ghL[NH3];
  __shared__ float ex2L[NS];
  __shared__ uint32_t keysL[2*NS];
  __shared__ float xpL[2];
  __shared__ float part[NWAVE][8];
  __shared__ int   partI[NWAVE];

  const int t = threadIdx.x;
  const int b = blockIdx.x;
  const int w = t >> 6;                    // wave 0..15
  const int s = t >> 2;                    // candidate node (quads)
  const int q = t & 3;                     // h-phase
  const bool activeS = (t < 4*NS);         // 800 task lanes

  // ---- one-time setup ----
  if (t < NS) {
    st0L[t] = stat[(size_t)b*2*NS + t];
    st1L[t] = stat[(size_t)b*2*NS + NS + t];
    dy0L[t] = dyn[(size_t)b*2*NS + t];
    dy1L[t] = dyn[(size_t)b*2*NS + NS + t];
    uint32_t q0, q1;
    threefry2x32(0u, 42u, 0u, (uint32_t)t, q0, q1);
    keysL[2*t] = q0; keysL[2*t + 1] = q1;
  }
  if (t < NH) {
    int h = t;
    const float* war = Wa + (size_t)h * NH3;
    float as0 = 0.f, as1 = 0.f, ad0 = 0.f, ad1 = 0.f, ac = 0.f;
    for (int k = 0; k < NH; ++k) {
      as0 = fmaf(war[k],     sW[k*2+0], as0);
      as1 = fmaf(war[k],     sW[k*2+1], as1);
      ad0 = fmaf(war[NH+k],  dW[k*2+0], ad0);
      ad1 = fmaf(war[NH+k],  dW[k*2+1], ad1);
      ac  = fmaf(war[k],     sb[k],     ac);
    }
    for (int k = 0; k < NH; ++k) ac = fmaf(war[NH+k], db[k], ac);
    AF4[h] = make_float4(as0, as1, ad0, ad1);
    HtVa[h] = make_float2(va[h], 0.f);
    AcL[h] = ac;

    const float* wdr = Wd + (size_t)h * 256;
    float ds0 = 0.f, ds1 = 0.f, dc = 0.f, c0 = 0.f, c1 = 0.f, cb = 0.f;
    for (int k = 0; k < NH; ++k) {
      ds0 = fmaf(wdr[k],    sW[k*2+0], ds0);
      ds1 = fmaf(wdr[k],    sW[k*2+1], ds1);
      dc  = fmaf(wdr[k],    sb[k],     dc);
      c0  = fmaf(wdr[NH+k], sW[k*2+0], c0);
      c1  = fmaf(wdr[NH+k], sW[k*2+1], c1);
      cb  = fmaf(wdr[NH+k], sb[k],     cb);
    }
    DF4[h] = make_float4(ds0, ds1, vd[h], 0.f);
    CW4[h] = make_float4(c0, c1, cb, dc);

    bembL[h] = bemb[h];
    WembL[2*h]   = Wemb[2*h];
    WembL[2*h+1] = Wemb[2*h+1];
    hL[h] = h0[h];
  }
  for (int i = t; i < NH3; i += NT) { bihL[i] = bih[i]; bhhL[i] = bhh[i]; }
  if (t == 0) { xpL[0] = x0[0]; xpL[1] = x0[1]; }
  __syncthreads();

  // per-s inputs hoisted (quad-uniform)
  float s0r = 0.f, s1r = 0.f, d0r = 0.f, d1r = 0.f;
  if (activeS) { s0r = st0L[s]; s1r = st1L[s]; d0r = dy0L[s]; d1r = dy1L[s]; }

  // ---- 200 decode steps ----
  for (int step = 0; step < NS; ++step) {
    // S0: emb = x @ Wemb^T + bemb (t<128)
    if (t < NH) {
      float e = fmaf(xpL[1], WembL[t*2+1], __fmul_rn(xpL[0], WembL[t*2+0]));
      embL[t] = __fadd_rn(e, bembL[t]);
    }
    __syncthreads();

    // S1: 768 GRU dots, 1 per lane, perfectly balanced (bit-exact chain)
    if (t < 2*NH3) {
      const bool isWih = (t < NH3);
      const float4* wp = isWih
          ? (const float4*)(Wih + (size_t)t * NH)
          : (const float4*)(Whh + (size_t)(t - NH3) * NH);
      const float4* op = isWih ? (const float4*)embL : (const float4*)hL;
      float a0 = 0.f;
      #pragma unroll 4
      for (int k4 = 0; k4 < 32; ++k4) {
        float4 c = wp[k4], v = op[k4];
        a0 = fmaf(c.x, v.x, a0); a0 = fmaf(c.y, v.y, a0);
        a0 = fmaf(c.z, v.z, a0); a0 = fmaf(c.w, v.w, a0);
      }
      if (isWih) giL[t]       = __fadd_rn(a0, bihL[t]);
      else       ghL[t - NH3] = __fadd_rn(a0, bhhL[t - NH3]);
    }
    __syncthreads();

    // S2: gates (torch r,z,n) EXACT XLA math, h_new in place (t<128)
    if (t < NH) {
      float r = xla_sigmoidf(__fadd_rn(giL[t],      ghL[t]));
      float z = xla_sigmoidf(__fadd_rn(giL[t+NH],   ghL[t+NH]));
      float n = xla_tanhf(__fadd_rn(giL[t+2*NH], __fmul_rn(r, ghL[t+2*NH])));
      float hv = hL[t];
      hL[t] = __fadd_rn(__fmul_rn(__fsub_rn(1.0f, z), n), __fmul_rn(z, hv));
    }
    __syncthreads();

    // S3: Hterm = Wa[:,256:384] @ h_new, +Ac, packed next to va (t<128)
    if (t < NH) {
      const float4* war = (const float4*)(Wa + (size_t)t*NH3 + 2*NH);
      const float4* hn4 = (const float4*)hL;
      float acc = 0.f;
      #pragma unroll 8
      for (int k4 = 0; k4 < 32; ++k4) {
        float4 a = war[k4], hv = hn4[k4];
        acc = fmaf(a.x, hv.x, acc); acc = fmaf(a.y, hv.y, acc);
        acc = fmaf(a.z, hv.z, acc); acc = fmaf(a.w, hv.w, acc);
      }
      HtVa[t].y = __fadd_rn(acc, AcL[t]);
    }
    __syncthreads();

    // S4: attention scores; quad map, broadcast-friendly LDS reads
    float acc = 0.f;
    if (activeS) {
      #pragma unroll 8
      for (int j = 0; j < 32; ++j) {
        int h = q + 4*j;
        float4 af = AF4[h];
        float2 hv = HtVa[h];
        float e = fmaf(af.x, s0r, hv.y);
        e = fmaf(af.y, s1r, e);
        e = fmaf(af.z, d0r, e);
        e = fmaf(af.w, d1r, e);
        acc = fmaf(hv.x, fast_tanhf(e), acc);
      }
    }
    // quad combine -> sc on all 4 quad lanes
    float v = __fadd_rn(acc, __shfl_xor(acc, 1));
    v = __fadd_rn(v, __shfl_xor(v, 2));
    float sc = activeS ? v : 0.f;

    // raw exp + sums (each s counted once: quad-uniform, xor 4..32)
    float exv = activeS ? __expf(sc) : 0.f;
    {
      float sm = exv;
      float c0 = __fmul_rn(exv, s0r);
      float c1 = __fmul_rn(exv, s1r);
      #pragma unroll
      for (int mm = 4; mm < 64; mm <<= 1) {
        sm = __fadd_rn(sm, __shfl_xor(sm, mm));
        c0 = __fadd_rn(c0, __shfl_xor(c0, mm));
        c1 = __fadd_rn(c1, __shfl_xor(c1, mm));
      }
      if ((t & 63) == 0) { part[w][0] = sm; part[w][1] = c0; part[w][2] = c1; }
    }
    __syncthreads();

    // Cterm: ct_full = Dc + (r0*Cw0 + r1*Cw1 + Cwb) -> DF4[t].w (t<128)
    if (t < NH) {
      float sume = part[0][0], r0 = part[0][1], r1 = part[0][2];
      #pragma unroll
      for (int ww = 1; ww < NWAVE; ++ww) {
        sume = __fadd_rn(sume, part[ww][0]);
        r0   = __fadd_rn(r0,   part[ww][1]);
        r1   = __fadd_rn(r1,   part[ww][2]);
      }
      r0 = __fdiv_rn(r0, sume); r1 = __fdiv_rn(r1, sume);
      float4 cw = CW4[t];
      float ct = fmaf(r0, cw.x, fmaf(r1, cw.y, cw.z));
      DF4[t].w = __fadd_rn(cw.w, ct);
    }
    __syncthreads();

    // S5: decoder logits; single float4 read per iter
    float accD = 0.f;
    if (activeS) {
      #pragma unroll 8
      for (int j = 0; j < 32; ++j) {
        int h = q + 4*j;
        float4 df = DF4[h];
        float d = fmaf(df.x, s0r, df.w);
        d = fmaf(df.y, s1r, d);
        accD = fmaf(df.z, fast_tanhf(d), accD);
      }
    }
    float v2 = __fadd_rn(accD, __shfl_xor(accD, 1));
    v2 = __fadd_rn(v2, __shfl_xor(v2, 2));
    float sc2 = activeS ? v2 : 0.f;

    // decoder raw exp/sum + gumbel argmax (merged butterfly)
    float e2 = activeS ? __expf(sc2) : 0.f;
    if (activeS && q == 0) ex2L[s] = e2;
    {
      uint32_t k0 = keysL[2*step], k1 = keysL[2*step + 1];
      float gv = -INFINITY;
      int gidx = 1 << 20;
      if (activeS) {
        uint32_t q0, q1;
        threefry2x32(k0, k1, 0u, (uint32_t)(b*NS + s), q0, q1);
        gv = __fadd_rn(bits_to_gumbel(q0 ^ q1), sc2);
        gidx = s;
      }
      float sm = e2;
      #pragma unroll
      for (int mm = 4; mm < 64; mm <<= 1) {
        sm = __fadd_rn(sm, __shfl_xor(sm, mm));
        float ov = __shfl_xor(gv, mm); int oi = __shfl_xor(gidx, mm);
        if (ov > gv || (ov == gv && oi < gidx)) { gv = ov; gidx = oi; }
      }
      if ((t & 63) == 0) { part[w][3] = sm; part[w][4] = gv; partI[w] = gidx; }
    }
    __syncthreads();

    if (t == 0) {
      float bv = part[0][4]; int bi = partI[0];
      float sume2 = part[0][3];
      #pragma unroll
      for (int ww = 1; ww < NWAVE; ++ww) {
        float vv = part[ww][4]; int ii = partI[ww];
        if (vv > bv || (vv == bv && ii < bi)) { bv = vv; bi = ii; }
        sume2 = __fadd_rn(sume2, part[ww][3]);
      }
      out[(size_t)b*NS + step] = (float)bi;
      out[(size_t)NB*NS + (size_t)b*NS + step] = __fdiv_rn(ex2L[bi], sume2);
      xpL[0] = st0L[bi]; xpL[1] = st1L[bi];
    }
    __syncthreads();
  }
}

// ---------------- host launch ----------------
extern "C" void kernel_launch(void* const* d_in, const int* in_sizes, int n_in,
                              void* d_out, int out_size, void* d_ws, size_t ws_size,
                              hipStream_t stream) {
  (void)in_sizes; (void)n_in; (void)out_size; (void)d_ws; (void)ws_size;
  const float* stat = (const float*)d_in[0];
  const float* dyn  = (const float*)d_in[1];
  const float* sW   = (const float*)d_in[2];
  const float* sb   = (const float*)d_in[3];
  const float* dW   = (const float*)d_in[4];
  const float* db   = (const float*)d_in[5];
  const float* x0   = (const float*)d_in[6];
  const float* h0   = (const float*)d_in[7];
  const float* Wemb = (const float*)d_in[8];
  const float* bemb = (const float*)d_in[9];
  const float* Wih  = (const float*)d_in[10];
  const float* Whh  = (const float*)d_in[11];
  const float* bih  = (const float*)d_in[12];
  const float* bhh  = (const float*)d_in[13];
  const float* Wa   = (const float*)d_in[14];
  const float* va   = (const float*)d_in[15];
  const float* Wd   = (const float*)d_in[16];
  const float* vd   = (const float*)d_in[17];
  float* out = (float*)d_out;

  k_decode<<<NB, NT, 0, stream>>>(stat, dyn, sW, sb, dW, db, x0, h0,
                                  Wemb, bemb, Wih, Whh, bih, bhh,
                                  Wa, va, Wd, vd, out);
}

// Round 12
// 6649.936 us; speedup vs baseline: 1.0265x; 1.0265x over previous
//
#include <hip/hip_runtime.h>
#include <stdint.h>
#include <math.h>

#define NB 512
#define NS 200
#define NH 128
#define NH3 384
#define NWAVE 8

// ---------------- XLA-exact scalar helpers (GRU gate path only) ----------------
__device__ __forceinline__ float xla_tanhf(float x) {
  float cx = fminf(fmaxf(x, -9.0f), 9.0f);
  float x2 = __fmul_rn(cx, cx);
  float p = -2.76076847742355e-16f;
  p = __fadd_rn(__fmul_rn(x2, p), 2.00018790482477e-13f);
  p = __fadd_rn(__fmul_rn(x2, p), -8.60467152213735e-11f);
  p = __fadd_rn(__fmul_rn(x2, p), 5.12229709037114e-08f);
  p = __fadd_rn(__fmul_rn(x2, p), 1.48572235717979e-05f);
  p = __fadd_rn(__fmul_rn(x2, p), 6.37261928875436e-04f);
  p = __fadd_rn(__fmul_rn(x2, p), 4.89352455891786e-03f);
  p = __fmul_rn(cx, p);
  float q = 1.19825839466702e-06f;
  q = __fadd_rn(__fmul_rn(x2, q), 1.18534705686654e-04f);
  q = __fadd_rn(__fmul_rn(x2, q), 2.26843463243900e-03f);
  q = __fadd_rn(__fmul_rn(x2, q), 4.89352518554385e-03f);
  float r = __fdiv_rn(p, q);
  return (fabsf(x) < 0.0004f) ? x : r;
}

__device__ __forceinline__ float xla_sigmoidf(float x) {
  return __fadd_rn(0.5f, __fmul_rn(0.5f, xla_tanhf(__fmul_rn(0.5f, x))));
}

// exp-based fast tanh for logit paths — validated r10 (absmax 0.0)
__device__ __forceinline__ float fast_tanhf(float x) {
  float e = __expf(__fmul_rn(x, 2.0f));
  float r = __builtin_amdgcn_rcpf(__fadd_rn(e, 1.0f));
  return fmaf(-2.0f, r, 1.0f);
}

__device__ __forceinline__ uint32_t rotl32(uint32_t v, int r) {
  return (v << r) | (v >> (32 - r));
}
__device__ __forceinline__ void threefry2x32(uint32_t k0, uint32_t k1,
                                             uint32_t x0, uint32_t x1,
                                             uint32_t& o0, uint32_t& o1) {
  uint32_t k2 = k0 ^ k1 ^ 0x1BD11BDAu;
  x0 += k0; x1 += k1;
  #define TFR(r) { x0 += x1; x1 = rotl32(x1, r); x1 ^= x0; }
  TFR(13) TFR(15) TFR(26) TFR(6)
  x0 += k1; x1 += k2 + 1u;
  TFR(17) TFR(29) TFR(16) TFR(24)
  x0 += k2; x1 += k0 + 2u;
  TFR(13) TFR(15) TFR(26) TFR(6)
  x0 += k0; x1 += k1 + 3u;
  TFR(17) TFR(29) TFR(16) TFR(24)
  x0 += k1; x1 += k2 + 4u;
  TFR(13) TFR(15) TFR(26) TFR(6)
  x0 += k2; x1 += k0 + 5u;
  #undef TFR
  o0 = x0; o1 = x1;
}

__device__ __forceinline__ float bits_to_gumbel(uint32_t bits) {
  const float kTiny = 1.1754943508222875e-38f;
  float f = __fsub_rn(__uint_as_float((bits >> 9) | 0x3F800000u), 1.0f);
  float u = __fadd_rn(__fmul_rn(f, __fsub_rn(1.0f, kTiny)), kTiny);
  u = fmaxf(kTiny, u);
  return -logf(-logf(u));
}

// ---------------- persistent kernel: 1 row/block, 512 threads ----------------
// Phases/step (7 barriers): B gi+gumbel | C gates | D Hterm+gh_next |
//                           E attn | F Cterm | G dec+sample | A combine+emb
__global__ __launch_bounds__(512, 4) void k_decode(
    const float* __restrict__ stat, const float* __restrict__ dyn,
    const float* __restrict__ sW,   const float* __restrict__ sb,
    const float* __restrict__ dW,   const float* __restrict__ db,
    const float* __restrict__ x0,   const float* __restrict__ h0,
    const float* __restrict__ Wemb, const float* __restrict__ bemb,
    const float* __restrict__ Wih,  const float* __restrict__ Whh,
    const float* __restrict__ bih,  const float* __restrict__ bhh,
    const float* __restrict__ Wa,   const float* __restrict__ va,
    const float* __restrict__ Wd,   const float* __restrict__ vd,
    float* __restrict__ out) {

  __shared__ __align__(16) float st0L[NS], st1L[NS], dy0L[NS], dy1L[NS];
  __shared__ float4 AF4[NH];               // {As0,As1,Ad0,Ad1}
  __shared__ float4 DF4[NH];               // {Ds0,Ds1,vd, ct_full(per-step)}
  __shared__ float4 CW4[NH];               // {Cw0,Cw1,Cwb,Dc}
  __shared__ float2 HtVa[NH];              // {va, Ht+Ac (per-step)}
  __shared__ float  AcL[NH];
  __shared__ float WembL[2*NH], bembL[NH];
  __shared__ float bihL[NH3], bhhL[NH3];
  __shared__ __align__(16) float embL[NH], hL[NH];
  __shared__ float giL[NH3], ghL[NH3];
  __shared__ float ex2L[NS], gumL[NS];
  __shared__ uint32_t keysL[2*NS];
  __shared__ float part[NWAVE][8];
  __shared__ int   partI[NWAVE];

  const int t = threadIdx.x;
  const int b = blockIdx.x;
  const int w = t >> 6;                    // wave 0..7
  const int s = t >> 1;                    // candidate node (lane pairs)
  const int h0i = (t & 1) * 64;            // h-half base
  const bool activeS = (t < 2*NS);         // 400 task lanes (E/G phases)

  // ---- one-time setup ----
  if (t < NS) {
    st0L[t] = stat[(size_t)b*2*NS + t];
    st1L[t] = stat[(size_t)b*2*NS + NS + t];
    dy0L[t] = dyn[(size_t)b*2*NS + t];
    dy1L[t] = dyn[(size_t)b*2*NS + NS + t];
    uint32_t q0, q1;
    threefry2x32(0u, 42u, 0u, (uint32_t)t, q0, q1);
    keysL[2*t] = q0; keysL[2*t + 1] = q1;
  }
  if (t < NH) {
    int h = t;
    const float* war = Wa + (size_t)h * NH3;
    float as0 = 0.f, as1 = 0.f, ad0 = 0.f, ad1 = 0.f, ac = 0.f;
    for (int k = 0; k < NH; ++k) {
      as0 = fmaf(war[k],     sW[k*2+0], as0);
      as1 = fmaf(war[k],     sW[k*2+1], as1);
      ad0 = fmaf(war[NH+k],  dW[k*2+0], ad0);
      ad1 = fmaf(war[NH+k],  dW[k*2+1], ad1);
      ac  = fmaf(war[k],     sb[k],     ac);
    }
    for (int k = 0; k < NH; ++k) ac = fmaf(war[NH+k], db[k], ac);
    AF4[h] = make_float4(as0, as1, ad0, ad1);
    HtVa[h] = make_float2(va[h], 0.f);
    AcL[h] = ac;

    const float* wdr = Wd + (size_t)h * 256;
    float ds0 = 0.f, ds1 = 0.f, dc = 0.f, c0 = 0.f, c1 = 0.f, cb = 0.f;
    for (int k = 0; k < NH; ++k) {
      ds0 = fmaf(wdr[k],    sW[k*2+0], ds0);
      ds1 = fmaf(wdr[k],    sW[k*2+1], ds1);
      dc  = fmaf(wdr[k],    sb[k],     dc);
      c0  = fmaf(wdr[NH+k], sW[k*2+0], c0);
      c1  = fmaf(wdr[NH+k], sW[k*2+1], c1);
      cb  = fmaf(wdr[NH+k], sb[k],     cb);
    }
    DF4[h] = make_float4(ds0, ds1, vd[h], 0.f);
    CW4[h] = make_float4(c0, c1, cb, dc);

    bembL[h] = bemb[h];
    WembL[2*h]   = Wemb[2*h];
    WembL[2*h+1] = Wemb[2*h+1];
    hL[h] = h0[h];
  }
  for (int i = t; i < NH3; i += 512) { bihL[i] = bih[i]; bhhL[i] = bhh[i]; }
  __syncthreads();

  // setup: initial emb (from x0) and initial gh = Whh@h0 + bhh
  if (t < NH) {
    float xa = x0[0], xb = x0[1];
    float e = fmaf(xb, WembL[t*2+1], __fmul_rn(xa, WembL[t*2+0]));
    embL[t] = __fadd_rn(e, bembL[t]);
  } else {
    int row = t - NH;                      // 0..383 over lanes 128..511
    const float4* wp = (const float4*)(Whh + (size_t)row * NH);
    const float4* h4 = (const float4*)hL;
    float a0 = 0.f;
    #pragma unroll 8
    for (int k4 = 0; k4 < 32; ++k4) {
      float4 c = wp[k4], v = h4[k4];
      a0 = fmaf(c.x, v.x, a0); a0 = fmaf(c.y, v.y, a0);
      a0 = fmaf(c.z, v.z, a0); a0 = fmaf(c.w, v.w, a0);
    }
    ghL[row] = __fadd_rn(a0, bhhL[row]);
  }
  // per-s inputs hoisted (pair-uniform)
  float s0r = 0.f, s1r = 0.f, d0r = 0.f, d1r = 0.f;
  if (activeS) { s0r = st0L[s]; s1r = st1L[s]; d0r = dy0L[s]; d1r = dy1L[s]; }
  __syncthreads();

  // ---- 200 decode steps ----
  for (int step = 0; step < NS; ++step) {
    // B: gi (384 lanes, bit-exact chains) + gumbel precompute (128 lanes)
    if (t < NH3) {
      const float4* wp = (const float4*)(Wih + (size_t)t * NH);
      const float4* op = (const float4*)embL;
      float a0 = 0.f;
      #pragma unroll 8
      for (int k4 = 0; k4 < 32; ++k4) {
        float4 c = wp[k4], v = op[k4];
        a0 = fmaf(c.x, v.x, a0); a0 = fmaf(c.y, v.y, a0);
        a0 = fmaf(c.z, v.z, a0); a0 = fmaf(c.w, v.w, a0);
      }
      giL[t] = __fadd_rn(a0, bihL[t]);
    } else {
      int si = t - NH3;                    // 0..127
      uint32_t k0 = keysL[2*step], k1 = keysL[2*step + 1];
      uint32_t q0, q1;
      threefry2x32(k0, k1, 0u, (uint32_t)(b*NS + si), q0, q1);
      gumL[si] = bits_to_gumbel(q0 ^ q1);
      if (si < NS - NH) {                  // si < 72 -> also s = si+128
        threefry2x32(k0, k1, 0u, (uint32_t)(b*NS + si + NH), q0, q1);
        gumL[si + NH] = bits_to_gumbel(q0 ^ q1);
      }
    }
    __syncthreads();

    // C: gates (torch r,z,n) EXACT XLA math, h_new in place (t<128)
    if (t < NH) {
      float r = xla_sigmoidf(__fadd_rn(giL[t],      ghL[t]));
      float z = xla_sigmoidf(__fadd_rn(giL[t+NH],   ghL[t+NH]));
      float n = xla_tanhf(__fadd_rn(giL[t+2*NH], __fmul_rn(r, ghL[t+2*NH])));
      float hv = hL[t];
      hL[t] = __fadd_rn(__fmul_rn(__fsub_rn(1.0f, z), n), __fmul_rn(z, hv));
    }
    __syncthreads();

    // D: Hterm (t<128) + gh for NEXT step (384 lanes) — 512/512 busy
    if (t < NH) {
      const float4* war = (const float4*)(Wa + (size_t)t*NH3 + 2*NH);
      const float4* hn4 = (const float4*)hL;
      float acc = 0.f;
      #pragma unroll 8
      for (int k4 = 0; k4 < 32; ++k4) {
        float4 a = war[k4], hv = hn4[k4];
        acc = fmaf(a.x, hv.x, acc); acc = fmaf(a.y, hv.y, acc);
        acc = fmaf(a.z, hv.z, acc); acc = fmaf(a.w, hv.w, acc);
      }
      HtVa[t].y = __fadd_rn(acc, AcL[t]);
    } else {
      int row = t - NH;
      const float4* wp = (const float4*)(Whh + (size_t)row * NH);
      const float4* h4 = (const float4*)hL;
      float a0 = 0.f;
      #pragma unroll 8
      for (int k4 = 0; k4 < 32; ++k4) {
        float4 c = wp[k4], v = h4[k4];
        a0 = fmaf(c.x, v.x, a0); a0 = fmaf(c.y, v.y, a0);
        a0 = fmaf(c.z, v.z, a0); a0 = fmaf(c.w, v.w, a0);
      }
      ghL[row] = __fadd_rn(a0, bhhL[row]);
    }
    __syncthreads();

    // E: attention scores; pair map, exp-tanh (r10-exact op order)
    float acc = 0.f;
    if (activeS) {
      #pragma unroll 4
      for (int j = 0; j < 64; ++j) {
        int h = h0i + j;
        float4 af = AF4[h];
        float2 hv = HtVa[h];
        float e = fmaf(af.y, s1r, __fmul_rn(af.x, s0r));
        e = fmaf(af.z, d0r, e);
        e = fmaf(af.w, d1r, e);
        e = __fadd_rn(e, hv.y);
        acc = fmaf(hv.x, fast_tanhf(e), acc);
      }
    }
    float sc = activeS ? __fadd_rn(acc, __shfl_xor(acc, 1)) : 0.f;

    // raw exp + sums butterfly (pair-uniform, xor 2..32)
    float exv = activeS ? __expf(sc) : 0.f;
    {
      float sm = exv;
      float c0 = __fmul_rn(exv, s0r);
      float c1 = __fmul_rn(exv, s1r);
      #pragma unroll
      for (int mm = 2; mm < 64; mm <<= 1) {
        sm = __fadd_rn(sm, __shfl_xor(sm, mm));
        c0 = __fadd_rn(c0, __shfl_xor(c0, mm));
        c1 = __fadd_rn(c1, __shfl_xor(c1, mm));
      }
      if ((t & 63) == 0) { part[w][0] = sm; part[w][1] = c0; part[w][2] = c1; }
    }
    __syncthreads();

    // F: Cterm -> DF4[t].w (t<128)
    if (t < NH) {
      float sume = part[0][0], r0 = part[0][1], r1 = part[0][2];
      #pragma unroll
      for (int ww = 1; ww < NWAVE; ++ww) {
        sume = __fadd_rn(sume, part[ww][0]);
        r0   = __fadd_rn(r0,   part[ww][1]);
        r1   = __fadd_rn(r1,   part[ww][2]);
      }
      r0 = __fdiv_rn(r0, sume); r1 = __fdiv_rn(r1, sume);
      float4 cw = CW4[t];
      float ct = fmaf(r0, cw.x, fmaf(r1, cw.y, cw.z));
      DF4[t].w = __fadd_rn(cw.w, ct);
    }
    __syncthreads();

    // G: decoder logits + sampling butterflies
    float accD = 0.f;
    if (activeS) {
      #pragma unroll 4
      for (int j = 0; j < 64; ++j) {
        int h = h0i + j;
        float4 df = DF4[h];
        float d = fmaf(df.x, s0r, df.w);
        d = fmaf(df.y, s1r, d);
        accD = fmaf(df.z, fast_tanhf(d), accD);
      }
    }
    float sc2 = activeS ? __fadd_rn(accD, __shfl_xor(accD, 1)) : 0.f;

    float e2 = activeS ? __expf(sc2) : 0.f;
    if (activeS && (t & 1) == 0) ex2L[s] = e2;
    {
      float gv = -INFINITY;
      int gidx = 1 << 20;
      if (activeS) {
        gv = __fadd_rn(gumL[s], sc2);
        gidx = s;
      }
      float sm = e2;
      #pragma unroll
      for (int mm = 2; mm < 64; mm <<= 1) {
        sm = __fadd_rn(sm, __shfl_xor(sm, mm));
        float ov = __shfl_xor(gv, mm); int oi = __shfl_xor(gidx, mm);
        if (ov > gv || (ov == gv && oi < gidx)) { gv = ov; gidx = oi; }
      }
      if ((t & 63) == 0) { part[w][3] = sm; part[w][4] = gv; partI[w] = gidx; }
    }
    __syncthreads();

    // A: ALL lanes combine winner; t==0 writes outputs; t<128 next emb
    {
      float bv = part[0][4]; int bi = partI[0];
      float sume2 = part[0][3];
      #pragma unroll
      for (int ww = 1; ww < NWAVE; ++ww) {
        float vv = part[ww][4]; int ii = partI[ww];
        if (vv > bv || (vv == bv && ii < bi)) { bv = vv; bi = ii; }
        sume2 = __fadd_rn(sume2, part[ww][3]);
      }
      if (t == 0) {
        out[(size_t)b*NS + step] = (float)bi;
        out[(size_t)NB*NS + (size_t)b*NS + step] = __fdiv_rn(ex2L[bi], sume2);
      }
      if (t < NH) {
        float xa = st0L[bi], xb = st1L[bi];
        float e = fmaf(xb, WembL[t*2+1], __fmul_rn(xa, WembL[t*2+0]));
        embL[t] = __fadd_rn(e, bembL[t]);
      }
    }
    __syncthreads();
  }
}

// ---------------- host launch ----------------
extern "C" void kernel_launch(void* const* d_in, const int* in_sizes, int n_in,
                              void* d_out, int out_size, void* d_ws, size_t ws_size,
                              hipStream_t stream) {
  (void)in_sizes; (void)n_in; (void)out_size; (void)d_ws; (void)ws_size;
  const float* stat = (const float*)d_in[0];
  const float* dyn  = (const float*)d_in[1];
  const float* sW   = (const float*)d_in[2];
  const float* sb   = (const float*)d_in[3];
  const float* dW   = (const float*)d_in[4];
  const float* db   = (const float*)d_in[5];
  const float* x0   = (const float*)d_in[6];
  const float* h0   = (const float*)d_in[7];
  const float* Wemb = (const float*)d_in[8];
  const float* bemb = (const float*)d_in[9];
  const float* Wih  = (const float*)d_in[10];
  const float* Whh  = (const float*)d_in[11];
  const float* bih  = (const float*)d_in[12];
  const float* bhh  = (const float*)d_in[13];
  const float* Wa   = (const float*)d_in[14];
  const float* va   = (const float*)d_in[15];
  const float* Wd   = (const float*)d_in[16];
  const float* vd   = (const float*)d_in[17];
  float* out = (float*)d_out;

  k_decode<<<NB, 512, 0, stream>>>(stat, dyn, sW, sb, dW, db, x0, h0,
                                   Wemb, bemb, Wih, Whh, bih, bhh,
                                   Wa, va, Wd, vd, out);
}

// Round 13
// 6600.327 us; speedup vs baseline: 1.0342x; 1.0075x over previous
//
#include <hip/hip_runtime.h>
#include <stdint.h>
#include <math.h>

#define NB 512
#define NS 200
#define NH 128
#define NH3 384
#define NWAVE 8

// padded LDS index maps: shift odd h-half by 64B (16 banks) — validated r9/r10
#define IDX4(h) ((h) + (((h) >> 6) << 2))    // float4: +4 per 64
#define IDX2(h) ((h) + (((h) >> 6) << 3))    // float2: +8 per 64

// ---------------- XLA-exact scalar helpers (GRU gate path only) ----------------
__device__ __forceinline__ float xla_tanhf(float x) {
  float cx = fminf(fmaxf(x, -9.0f), 9.0f);
  float x2 = __fmul_rn(cx, cx);
  float p = -2.76076847742355e-16f;
  p = __fadd_rn(__fmul_rn(x2, p), 2.00018790482477e-13f);
  p = __fadd_rn(__fmul_rn(x2, p), -8.60467152213735e-11f);
  p = __fadd_rn(__fmul_rn(x2, p), 5.12229709037114e-08f);
  p = __fadd_rn(__fmul_rn(x2, p), 1.48572235717979e-05f);
  p = __fadd_rn(__fmul_rn(x2, p), 6.37261928875436e-04f);
  p = __fadd_rn(__fmul_rn(x2, p), 4.89352455891786e-03f);
  p = __fmul_rn(cx, p);
  float q = 1.19825839466702e-06f;
  q = __fadd_rn(__fmul_rn(x2, q), 1.18534705686654e-04f);
  q = __fadd_rn(__fmul_rn(x2, q), 2.26843463243900e-03f);
  q = __fadd_rn(__fmul_rn(x2, q), 4.89352518554385e-03f);
  float r = __fdiv_rn(p, q);
  return (fabsf(x) < 0.0004f) ? x : r;
}

__device__ __forceinline__ float xla_sigmoidf(float x) {
  return __fadd_rn(0.5f, __fmul_rn(0.5f, xla_tanhf(__fmul_rn(0.5f, x))));
}

// exp-based fast tanh for logit paths — validated r10 (absmax 0.0)
__device__ __forceinline__ float fast_tanhf(float x) {
  float e = __expf(__fmul_rn(x, 2.0f));
  float r = __builtin_amdgcn_rcpf(__fadd_rn(e, 1.0f));
  return fmaf(-2.0f, r, 1.0f);
}

__device__ __forceinline__ uint32_t rotl32(uint32_t v, int r) {
  return (v << r) | (v >> (32 - r));
}
__device__ __forceinline__ void threefry2x32(uint32_t k0, uint32_t k1,
                                             uint32_t x0, uint32_t x1,
                                             uint32_t& o0, uint32_t& o1) {
  uint32_t k2 = k0 ^ k1 ^ 0x1BD11BDAu;
  x0 += k0; x1 += k1;
  #define TFR(r) { x0 += x1; x1 = rotl32(x1, r); x1 ^= x0; }
  TFR(13) TFR(15) TFR(26) TFR(6)
  x0 += k1; x1 += k2 + 1u;
  TFR(17) TFR(29) TFR(16) TFR(24)
  x0 += k2; x1 += k0 + 2u;
  TFR(13) TFR(15) TFR(26) TFR(6)
  x0 += k0; x1 += k1 + 3u;
  TFR(17) TFR(29) TFR(16) TFR(24)
  x0 += k1; x1 += k2 + 4u;
  TFR(13) TFR(15) TFR(26) TFR(6)
  x0 += k2; x1 += k0 + 5u;
  #undef TFR
  o0 = x0; o1 = x1;
}

__device__ __forceinline__ float bits_to_gumbel(uint32_t bits) {
  const float kTiny = 1.1754943508222875e-38f;
  float f = __fsub_rn(__uint_as_float((bits >> 9) | 0x3F800000u), 1.0f);
  float u = __fadd_rn(__fmul_rn(f, __fsub_rn(1.0f, kTiny)), kTiny);
  u = fmaxf(kTiny, u);
  return -logf(-logf(u));
}

// ---------------- persistent kernel: 1 row/block, 512 threads ----------------
// Phases/step (7 barriers): B gi+gumbel | C gates | D Hterm+gh_next |
//                           E attn | F Cterm | G dec+sample | A combine+emb
__global__ __launch_bounds__(512, 4) void k_decode(
    const float* __restrict__ stat, const float* __restrict__ dyn,
    const float* __restrict__ sW,   const float* __restrict__ sb,
    const float* __restrict__ dW,   const float* __restrict__ db,
    const float* __restrict__ x0,   const float* __restrict__ h0,
    const float* __restrict__ Wemb, const float* __restrict__ bemb,
    const float* __restrict__ Wih,  const float* __restrict__ Whh,
    const float* __restrict__ bih,  const float* __restrict__ bhh,
    const float* __restrict__ Wa,   const float* __restrict__ va,
    const float* __restrict__ Wd,   const float* __restrict__ vd,
    float* __restrict__ out) {

  __shared__ __align__(16) float st0L[NS], st1L[NS], dy0L[NS], dy1L[NS];
  __shared__ float4 AF4p[132];             // {As0,As1,Ad0,Ad1} padded
  __shared__ float4 DF4p[132];             // {Ds0,Ds1,vd, ct_full} padded
  __shared__ float4 CW4[NH];               // {Cw0,Cw1,Cwb,Dc}
  __shared__ float2 HtVaP[136];            // {va, Ht+Ac} padded
  __shared__ float  AcL[NH];
  __shared__ float WembL[2*NH], bembL[NH];
  __shared__ float bihL[NH3], bhhL[NH3];
  __shared__ __align__(16) float embL[NH], hL[NH];
  __shared__ float giL[NH3], ghL[NH3];
  __shared__ float ex2L[NS], gumL[NS];
  __shared__ uint32_t keysL[2*NS];
  __shared__ float part[NWAVE][8];
  __shared__ int   partI[NWAVE];

  const int t = threadIdx.x;
  const int b = blockIdx.x;
  const int w = t >> 6;                    // wave 0..7
  const int s = t >> 1;                    // candidate node (lane pairs)
  const int h0i = (t & 1) * 64;            // h-half base
  const int b4 = h0i + ((h0i >> 6) << 2);  // padded float4 base (0 or 68)
  const int b2 = h0i + ((h0i >> 6) << 3);  // padded float2 base (0 or 72)
  const bool activeS = (t < 2*NS);         // 400 task lanes (E/G phases)

  // ---- one-time setup ----
  if (t < NS) {
    st0L[t] = stat[(size_t)b*2*NS + t];
    st1L[t] = stat[(size_t)b*2*NS + NS + t];
    dy0L[t] = dyn[(size_t)b*2*NS + t];
    dy1L[t] = dyn[(size_t)b*2*NS + NS + t];
    uint32_t q0, q1;
    threefry2x32(0u, 42u, 0u, (uint32_t)t, q0, q1);
    keysL[2*t] = q0; keysL[2*t + 1] = q1;
  }
  if (t < NH) {
    int h = t;
    const float* war = Wa + (size_t)h * NH3;
    float as0 = 0.f, as1 = 0.f, ad0 = 0.f, ad1 = 0.f, ac = 0.f;
    for (int k = 0; k < NH; ++k) {
      as0 = fmaf(war[k],     sW[k*2+0], as0);
      as1 = fmaf(war[k],     sW[k*2+1], as1);
      ad0 = fmaf(war[NH+k],  dW[k*2+0], ad0);
      ad1 = fmaf(war[NH+k],  dW[k*2+1], ad1);
      ac  = fmaf(war[k],     sb[k],     ac);
    }
    for (int k = 0; k < NH; ++k) ac = fmaf(war[NH+k], db[k], ac);
    AF4p[IDX4(h)] = make_float4(as0, as1, ad0, ad1);
    HtVaP[IDX2(h)] = make_float2(va[h], 0.f);
    AcL[h] = ac;

    const float* wdr = Wd + (size_t)h * 256;
    float ds0 = 0.f, ds1 = 0.f, dc = 0.f, c0 = 0.f, c1 = 0.f, cb = 0.f;
    for (int k = 0; k < NH; ++k) {
      ds0 = fmaf(wdr[k],    sW[k*2+0], ds0);
      ds1 = fmaf(wdr[k],    sW[k*2+1], ds1);
      dc  = fmaf(wdr[k],    sb[k],     dc);
      c0  = fmaf(wdr[NH+k], sW[k*2+0], c0);
      c1  = fmaf(wdr[NH+k], sW[k*2+1], c1);
      cb  = fmaf(wdr[NH+k], sb[k],     cb);
    }
    DF4p[IDX4(h)] = make_float4(ds0, ds1, vd[h], 0.f);
    CW4[h] = make_float4(c0, c1, cb, dc);

    bembL[h] = bemb[h];
    WembL[2*h]   = Wemb[2*h];
    WembL[2*h+1] = Wemb[2*h+1];
    hL[h] = h0[h];
  }
  for (int i = t; i < NH3; i += 512) { bihL[i] = bih[i]; bhhL[i] = bhh[i]; }
  __syncthreads();

  // setup: initial emb (from x0) and initial gh = Whh@h0 + bhh
  if (t < NH) {
    float xa = x0[0], xb = x0[1];
    float e = fmaf(xb, WembL[t*2+1], __fmul_rn(xa, WembL[t*2+0]));
    embL[t] = __fadd_rn(e, bembL[t]);
  } else {
    int row = t - NH;                      // 0..383 over lanes 128..511
    const float4* wp = (const float4*)(Whh + (size_t)row * NH);
    const float4* h4 = (const float4*)hL;
    float a0 = 0.f;
    #pragma unroll 8
    for (int k4 = 0; k4 < 32; ++k4) {
      float4 c = wp[k4], v = h4[k4];
      a0 = fmaf(c.x, v.x, a0); a0 = fmaf(c.y, v.y, a0);
      a0 = fmaf(c.z, v.z, a0); a0 = fmaf(c.w, v.w, a0);
    }
    ghL[row] = __fadd_rn(a0, bhhL[row]);
  }
  // per-s inputs hoisted (pair-uniform)
  float s0r = 0.f, s1r = 0.f, d0r = 0.f, d1r = 0.f;
  if (activeS) { s0r = st0L[s]; s1r = st1L[s]; d0r = dy0L[s]; d1r = dy1L[s]; }
  __syncthreads();

  // ---- 200 decode steps ----
  for (int step = 0; step < NS; ++step) {
    // B: gi (384 lanes, bit-exact chains) + gumbel precompute (128 lanes)
    if (t < NH3) {
      const float4* wp = (const float4*)(Wih + (size_t)t * NH);
      const float4* op = (const float4*)embL;
      float a0 = 0.f;
      #pragma unroll 8
      for (int k4 = 0; k4 < 32; ++k4) {
        float4 c = wp[k4], v = op[k4];
        a0 = fmaf(c.x, v.x, a0); a0 = fmaf(c.y, v.y, a0);
        a0 = fmaf(c.z, v.z, a0); a0 = fmaf(c.w, v.w, a0);
      }
      giL[t] = __fadd_rn(a0, bihL[t]);
    } else {
      int si = t - NH3;                    // 0..127
      uint32_t k0 = keysL[2*step], k1 = keysL[2*step + 1];
      uint32_t q0, q1;
      threefry2x32(k0, k1, 0u, (uint32_t)(b*NS + si), q0, q1);
      gumL[si] = bits_to_gumbel(q0 ^ q1);
      if (si < NS - NH) {                  // si < 72 -> also s = si+128
        threefry2x32(k0, k1, 0u, (uint32_t)(b*NS + si + NH), q0, q1);
        gumL[si + NH] = bits_to_gumbel(q0 ^ q1);
      }
    }
    __syncthreads();

    // C: gates (torch r,z,n) EXACT XLA math, h_new in place (t<128)
    if (t < NH) {
      float r = xla_sigmoidf(__fadd_rn(giL[t],      ghL[t]));
      float z = xla_sigmoidf(__fadd_rn(giL[t+NH],   ghL[t+NH]));
      float n = xla_tanhf(__fadd_rn(giL[t+2*NH], __fmul_rn(r, ghL[t+2*NH])));
      float hv = hL[t];
      hL[t] = __fadd_rn(__fmul_rn(__fsub_rn(1.0f, z), n), __fmul_rn(z, hv));
    }
    __syncthreads();

    // D: Hterm (t<128) + gh for NEXT step (384 lanes) — 512/512 busy
    if (t < NH) {
      const float4* war = (const float4*)(Wa + (size_t)t*NH3 + 2*NH);
      const float4* hn4 = (const float4*)hL;
      float acc = 0.f;
      #pragma unroll 8
      for (int k4 = 0; k4 < 32; ++k4) {
        float4 a = war[k4], hv = hn4[k4];
        acc = fmaf(a.x, hv.x, acc); acc = fmaf(a.y, hv.y, acc);
        acc = fmaf(a.z, hv.z, acc); acc = fmaf(a.w, hv.w, acc);
      }
      HtVaP[IDX2(t)].y = __fadd_rn(acc, AcL[t]);
    } else {
      int row = t - NH;
      const float4* wp = (const float4*)(Whh + (size_t)row * NH);
      const float4* h4 = (const float4*)hL;
      float a0 = 0.f;
      #pragma unroll 8
      for (int k4 = 0; k4 < 32; ++k4) {
        float4 c = wp[k4], v = h4[k4];
        a0 = fmaf(c.x, v.x, a0); a0 = fmaf(c.y, v.y, a0);
        a0 = fmaf(c.z, v.z, a0); a0 = fmaf(c.w, v.w, a0);
      }
      ghL[row] = __fadd_rn(a0, bhhL[row]);
    }
    __syncthreads();

    // E: attention scores; pair map, padded LDS (conflict-free)
    float acc = 0.f;
    if (activeS) {
      #pragma unroll 4
      for (int j = 0; j < 64; ++j) {
        float4 af = AF4p[b4 + j];
        float2 hv = HtVaP[b2 + j];
        float e = fmaf(af.y, s1r, __fmul_rn(af.x, s0r));
        e = fmaf(af.z, d0r, e);
        e = fmaf(af.w, d1r, e);
        e = __fadd_rn(e, hv.y);
        acc = fmaf(hv.x, fast_tanhf(e), acc);
      }
    }
    float sc = activeS ? __fadd_rn(acc, __shfl_xor(acc, 1)) : 0.f;

    // raw exp + sums butterfly (pair-uniform, xor 2..32)
    float exv = activeS ? __expf(sc) : 0.f;
    {
      float sm = exv;
      float c0 = __fmul_rn(exv, s0r);
      float c1 = __fmul_rn(exv, s1r);
      #pragma unroll
      for (int mm = 2; mm < 64; mm <<= 1) {
        sm = __fadd_rn(sm, __shfl_xor(sm, mm));
        c0 = __fadd_rn(c0, __shfl_xor(c0, mm));
        c1 = __fadd_rn(c1, __shfl_xor(c1, mm));
      }
      if ((t & 63) == 0) { part[w][0] = sm; part[w][1] = c0; part[w][2] = c1; }
    }
    __syncthreads();

    // F: Cterm -> DF4p[t].w (t<128)
    if (t < NH) {
      float sume = part[0][0], r0 = part[0][1], r1 = part[0][2];
      #pragma unroll
      for (int ww = 1; ww < NWAVE; ++ww) {
        sume = __fadd_rn(sume, part[ww][0]);
        r0   = __fadd_rn(r0,   part[ww][1]);
        r1   = __fadd_rn(r1,   part[ww][2]);
      }
      r0 = __fdiv_rn(r0, sume); r1 = __fdiv_rn(r1, sume);
      float4 cw = CW4[t];
      float ct = fmaf(r0, cw.x, fmaf(r1, cw.y, cw.z));
      DF4p[IDX4(t)].w = __fadd_rn(cw.w, ct);
    }
    __syncthreads();

    // G: decoder logits + sampling butterflies (padded reads)
    float accD = 0.f;
    if (activeS) {
      #pragma unroll 4
      for (int j = 0; j < 64; ++j) {
        float4 df = DF4p[b4 + j];
        float d = fmaf(df.x, s0r, df.w);
        d = fmaf(df.y, s1r, d);
        accD = fmaf(df.z, fast_tanhf(d), accD);
      }
    }
    float sc2 = activeS ? __fadd_rn(accD, __shfl_xor(accD, 1)) : 0.f;

    float e2 = activeS ? __expf(sc2) : 0.f;
    if (activeS && (t & 1) == 0) ex2L[s] = e2;
    {
      float gv = -INFINITY;
      int gidx = 1 << 20;
      if (activeS) {
        gv = __fadd_rn(gumL[s], sc2);
        gidx = s;
      }
      float sm = e2;
      #pragma unroll
      for (int mm = 2; mm < 64; mm <<= 1) {
        sm = __fadd_rn(sm, __shfl_xor(sm, mm));
        float ov = __shfl_xor(gv, mm); int oi = __shfl_xor(gidx, mm);
        if (ov > gv || (ov == gv && oi < gidx)) { gv = ov; gidx = oi; }
      }
      if ((t & 63) == 0) { part[w][3] = sm; part[w][4] = gv; partI[w] = gidx; }
    }
    __syncthreads();

    // A: ALL lanes combine winner; t==0 writes outputs; t<128 next emb
    {
      float bv = part[0][4]; int bi = partI[0];
      float sume2 = part[0][3];
      #pragma unroll
      for (int ww = 1; ww < NWAVE; ++ww) {
        float vv = part[ww][4]; int ii = partI[ww];
        if (vv > bv || (vv == bv && ii < bi)) { bv = vv; bi = ii; }
        sume2 = __fadd_rn(sume2, part[ww][3]);
      }
      if (t == 0) {
        out[(size_t)b*NS + step] = (float)bi;
        out[(size_t)NB*NS + (size_t)b*NS + step] = __fdiv_rn(ex2L[bi], sume2);
      }
      if (t < NH) {
        float xa = st0L[bi], xb = st1L[bi];
        float e = fmaf(xb, WembL[t*2+1], __fmul_rn(xa, WembL[t*2+0]));
        embL[t] = __fadd_rn(e, bembL[t]);
      }
    }
    __syncthreads();
  }
}

// ---------------- host launch ----------------
extern "C" void kernel_launch(void* const* d_in, const int* in_sizes, int n_in,
                              void* d_out, int out_size, void* d_ws, size_t ws_size,
                              hipStream_t stream) {
  (void)in_sizes; (void)n_in; (void)out_size; (void)d_ws; (void)ws_size;
  const float* stat = (const float*)d_in[0];
  const float* dyn  = (const float*)d_in[1];
  const float* sW   = (const float*)d_in[2];
  const float* sb   = (const float*)d_in[3];
  const float* dW   = (const float*)d_in[4];
  const float* db   = (const float*)d_in[5];
  const float* x0   = (const float*)d_in[6];
  const float* h0   = (const float*)d_in[7];
  const float* Wemb = (const float*)d_in[8];
  const float* bemb = (const float*)d_in[9];
  const float* Wih  = (const float*)d_in[10];
  const float* Whh  = (const float*)d_in[11];
  const float* bih  = (const float*)d_in[12];
  const float* bhh  = (const float*)d_in[13];
  const float* Wa   = (const float*)d_in[14];
  const float* va   = (const float*)d_in[15];
  const float* Wd   = (const float*)d_in[16];
  const float* vd   = (const float*)d_in[17];
  float* out = (float*)d_out;

  k_decode<<<NB, 512, 0, stream>>>(stat, dyn, sW, sb, dW, db, x0, h0,
                                   Wemb, bemb, Wih, Whh, bih, bhh,
                                   Wa, va, Wd, vd, out);
}

// Round 14
// 5891.517 us; speedup vs baseline: 1.1586x; 1.1203x over previous
//
#include <hip/hip_runtime.h>
#include <stdint.h>
#include <math.h>

#define NB 512
#define NS 200
#define NH 128
#define NH3 384
#define NWAVE 8

// padded LDS index maps (break half-offset bank aliasing) — validated r9/r10
#define IDX4(h) ((h) + (((h) >> 6) << 2))    // float4: +4 per 64
#define IDX2(h) ((h) + (((h) >> 6) << 3))    // float2: +8 per 64

// ---------------- XLA-exact scalar helpers (GRU gate path only) ----------------
__device__ __forceinline__ float xla_tanhf(float x) {
  float cx = fminf(fmaxf(x, -9.0f), 9.0f);
  float x2 = __fmul_rn(cx, cx);
  float p = -2.76076847742355e-16f;
  p = __fadd_rn(__fmul_rn(x2, p), 2.00018790482477e-13f);
  p = __fadd_rn(__fmul_rn(x2, p), -8.60467152213735e-11f);
  p = __fadd_rn(__fmul_rn(x2, p), 5.12229709037114e-08f);
  p = __fadd_rn(__fmul_rn(x2, p), 1.48572235717979e-05f);
  p = __fadd_rn(__fmul_rn(x2, p), 6.37261928875436e-04f);
  p = __fadd_rn(__fmul_rn(x2, p), 4.89352455891786e-03f);
  p = __fmul_rn(cx, p);
  float q = 1.19825839466702e-06f;
  q = __fadd_rn(__fmul_rn(x2, q), 1.18534705686654e-04f);
  q = __fadd_rn(__fmul_rn(x2, q), 2.26843463243900e-03f);
  q = __fadd_rn(__fmul_rn(x2, q), 4.89352518554385e-03f);
  float r = __fdiv_rn(p, q);
  return (fabsf(x) < 0.0004f) ? x : r;
}

__device__ __forceinline__ float xla_sigmoidf(float x) {
  return __fadd_rn(0.5f, __fmul_rn(0.5f, xla_tanhf(__fmul_rn(0.5f, x))));
}

__device__ __forceinline__ uint32_t rotl32(uint32_t v, int r) {
  return (v << r) | (v >> (32 - r));
}
__device__ __forceinline__ void threefry2x32(uint32_t k0, uint32_t k1,
                                             uint32_t x0, uint32_t x1,
                                             uint32_t& o0, uint32_t& o1) {
  uint32_t k2 = k0 ^ k1 ^ 0x1BD11BDAu;
  x0 += k0; x1 += k1;
  #define TFR(r) { x0 += x1; x1 = rotl32(x1, r); x1 ^= x0; }
  TFR(13) TFR(15) TFR(26) TFR(6)
  x0 += k1; x1 += k2 + 1u;
  TFR(17) TFR(29) TFR(16) TFR(24)
  x0 += k2; x1 += k0 + 2u;
  TFR(13) TFR(15) TFR(26) TFR(6)
  x0 += k0; x1 += k1 + 3u;
  TFR(17) TFR(29) TFR(16) TFR(24)
  x0 += k1; x1 += k2 + 4u;
  TFR(13) TFR(15) TFR(26) TFR(6)
  x0 += k2; x1 += k0 + 5u;
  #undef TFR
  o0 = x0; o1 = x1;
}

__device__ __forceinline__ float bits_to_gumbel(uint32_t bits) {
  const float kTiny = 1.1754943508222875e-38f;
  float f = __fsub_rn(__uint_as_float((bits >> 9) | 0x3F800000u), 1.0f);
  float u = __fadd_rn(__fmul_rn(f, __fsub_rn(1.0f, kTiny)), kTiny);
  u = fmaxf(kTiny, u);
  return -logf(-logf(u));
}

// ---------------- persistent kernel: 1 row/block, 512 threads (r10 shell) ----
// S0 emb+gumbel | S1 768 dots | S2 gates | S3 Hterm | E attn | F Cterm |
// G dec+sample | A winner      (8 barriers/step)
__global__ __launch_bounds__(512, 4) void k_decode(
    const float* __restrict__ stat, const float* __restrict__ dyn,
    const float* __restrict__ sW,   const float* __restrict__ sb,
    const float* __restrict__ dW,   const float* __restrict__ db,
    const float* __restrict__ x0,   const float* __restrict__ h0,
    const float* __restrict__ Wemb, const float* __restrict__ bemb,
    const float* __restrict__ Wih,  const float* __restrict__ Whh,
    const float* __restrict__ bih,  const float* __restrict__ bhh,
    const float* __restrict__ Wa,   const float* __restrict__ va,
    const float* __restrict__ Wd,   const float* __restrict__ vd,
    float* __restrict__ out) {

  __shared__ __align__(16) float st0L[NS], st1L[NS], dy0L[NS], dy1L[NS];
  __shared__ float4 AF4p[132];             // {2As0,2As1,2Ad0,2Ad1} padded
  __shared__ float4 DF4p[132];             // {2Ds0,2Ds1,vd, ct2(per-step)} padded
  __shared__ float4 CW4[NH];               // {2Cw0,2Cw1,2Cwb,2Dc}
  __shared__ float2 HtVaP[136];            // {va, 2(Ht+Ac) (per-step)} padded
  __shared__ float  AcL[NH];
  __shared__ float WembL[2*NH], bembL[NH];
  __shared__ float bihL[NH3], bhhL[NH3];
  __shared__ __align__(16) float embL[NH], hL[NH];
  __shared__ float giL[NH3], ghL[NH3];
  __shared__ float ex2L[NS], gumL[NS];
  __shared__ uint32_t keysL[2*NS];
  __shared__ float xpL[2];
  __shared__ float SvL[2];                 // {Sva, Svd}
  __shared__ float part[NWAVE][8];
  __shared__ int   partI[NWAVE];

  const int t = threadIdx.x;
  const int b = blockIdx.x;
  const int w = t >> 6;                    // wave 0..7
  const int s = t >> 1;                    // candidate node (lane pairs)
  const int h0i = (t & 1) * 64;            // h-half base
  const int b4 = h0i + ((h0i >> 6) << 2);  // padded float4 base (0 or 68)
  const int b2 = h0i + ((h0i >> 6) << 3);  // padded float2 base (0 or 72)
  const bool activeS = (t < 2*NS);         // 400 task lanes (E/G)

  // ---- one-time setup ----
  if (t < NS) {
    st0L[t] = stat[(size_t)b*2*NS + t];
    st1L[t] = stat[(size_t)b*2*NS + NS + t];
    dy0L[t] = dyn[(size_t)b*2*NS + t];
    dy1L[t] = dyn[(size_t)b*2*NS + NS + t];
    uint32_t q0, q1;
    threefry2x32(0u, 42u, 0u, (uint32_t)t, q0, q1);
    keysL[2*t] = q0; keysL[2*t + 1] = q1;
  }
  if (t < NH) {
    int h = t;
    const float* war = Wa + (size_t)h * NH3;
    float as0 = 0.f, as1 = 0.f, ad0 = 0.f, ad1 = 0.f, ac = 0.f;
    for (int k = 0; k < NH; ++k) {
      as0 = fmaf(war[k],     sW[k*2+0], as0);
      as1 = fmaf(war[k],     sW[k*2+1], as1);
      ad0 = fmaf(war[NH+k],  dW[k*2+0], ad0);
      ad1 = fmaf(war[NH+k],  dW[k*2+1], ad1);
      ac  = fmaf(war[k],     sb[k],     ac);
    }
    for (int k = 0; k < NH; ++k) ac = fmaf(war[NH+k], db[k], ac);
    // pre-doubled (exact x2) for exp-tanh
    AF4p[IDX4(h)] = make_float4(2.f*as0, 2.f*as1, 2.f*ad0, 2.f*ad1);
    HtVaP[IDX2(h)] = make_float2(va[h], 0.f);
    AcL[h] = ac;

    const float* wdr = Wd + (size_t)h * 256;
    float ds0 = 0.f, ds1 = 0.f, dc = 0.f, c0 = 0.f, c1 = 0.f, cb = 0.f;
    for (int k = 0; k < NH; ++k) {
      ds0 = fmaf(wdr[k],    sW[k*2+0], ds0);
      ds1 = fmaf(wdr[k],    sW[k*2+1], ds1);
      dc  = fmaf(wdr[k],    sb[k],     dc);
      c0  = fmaf(wdr[NH+k], sW[k*2+0], c0);
      c1  = fmaf(wdr[NH+k], sW[k*2+1], c1);
      cb  = fmaf(wdr[NH+k], sb[k],     cb);
    }
    DF4p[IDX4(h)] = make_float4(2.f*ds0, 2.f*ds1, vd[h], 0.f);
    CW4[h] = make_float4(2.f*c0, 2.f*c1, 2.f*cb, 2.f*dc);

    bembL[h] = bemb[h];
    WembL[2*h]   = Wemb[2*h];
    WembL[2*h+1] = Wemb[2*h+1];
    hL[h] = h0[h];
  }
  for (int i = t; i < NH3; i += 512) { bihL[i] = bih[i]; bhhL[i] = bhh[i]; }
  if (t == 0) {
    xpL[0] = x0[0]; xpL[1] = x0[1];
    float sva = 0.f, svd = 0.f;
    for (int h = 0; h < NH; ++h) { sva = __fadd_rn(sva, va[h]); svd = __fadd_rn(svd, vd[h]); }
    SvL[0] = sva; SvL[1] = svd;
  }
  __syncthreads();

  // per-s inputs hoisted (pair-uniform)
  float s0r = 0.f, s1r = 0.f, d0r = 0.f, d1r = 0.f;
  if (activeS) { s0r = st0L[s]; s1r = st1L[s]; d0r = dy0L[s]; d1r = dy1L[s]; }
  const float svaR = SvL[0], svdR = SvL[1];

  // ---- 200 decode steps ----
  for (int step = 0; step < NS; ++step) {
    // S0: emb (t<128) + gumbel precompute on idle lanes (t in [128,328))
    if (t < NH) {
      float e = fmaf(xpL[1], WembL[t*2+1], __fmul_rn(xpL[0], WembL[t*2+0]));
      embL[t] = __fadd_rn(e, bembL[t]);
    } else if (t < NH + NS) {
      int si = t - NH;
      uint32_t k0 = keysL[2*step], k1 = keysL[2*step + 1];
      uint32_t q0, q1;
      threefry2x32(k0, k1, 0u, (uint32_t)(b*NS + si), q0, q1);
      gumL[si] = bits_to_gumbel(q0 ^ q1);
    }
    __syncthreads();

    // S1: 768 GRU dots over 512 threads (per-dot chain bit-identical r5-r10)
    if (t < 256) {
      const float4* wp0 = (const float4*)(Wih + (size_t)t * NH);
      const float4* wp1 = (const float4*)(Whh + (size_t)(NH + t) * NH);
      const float4* e4 = (const float4*)embL;
      const float4* h4 = (const float4*)hL;
      float a0 = 0.f, a1 = 0.f;
      #pragma unroll 8
      for (int k4 = 0; k4 < 32; ++k4) {
        float4 c0 = wp0[k4], c1 = wp1[k4];
        float4 ev = e4[k4],  hv = h4[k4];
        a0 = fmaf(c0.x, ev.x, a0); a0 = fmaf(c0.y, ev.y, a0);
        a0 = fmaf(c0.z, ev.z, a0); a0 = fmaf(c0.w, ev.w, a0);
        a1 = fmaf(c1.x, hv.x, a1); a1 = fmaf(c1.y, hv.y, a1);
        a1 = fmaf(c1.z, hv.z, a1); a1 = fmaf(c1.w, hv.w, a1);
      }
      giL[t]      = __fadd_rn(a0, bihL[t]);
      ghL[NH + t] = __fadd_rn(a1, bhhL[NH + t]);
    } else {
      const bool isWih = (t < NH3);
      const float4* wp = isWih
          ? (const float4*)(Wih + (size_t)t * NH)
          : (const float4*)(Whh + (size_t)(t - NH3) * NH);
      const float4* op = isWih ? (const float4*)embL : (const float4*)hL;
      float a0 = 0.f;
      #pragma unroll 8
      for (int k4 = 0; k4 < 32; ++k4) {
        float4 c = wp[k4], v = op[k4];
        a0 = fmaf(c.x, v.x, a0); a0 = fmaf(c.y, v.y, a0);
        a0 = fmaf(c.z, v.z, a0); a0 = fmaf(c.w, v.w, a0);
      }
      if (isWih) giL[t]       = __fadd_rn(a0, bihL[t]);
      else       ghL[t - NH3] = __fadd_rn(a0, bhhL[t - NH3]);
    }
    __syncthreads();

    // S2: gates (torch r,z,n) EXACT XLA math, h_new in place (t<128)
    if (t < NH) {
      float r = xla_sigmoidf(__fadd_rn(giL[t],      ghL[t]));
      float z = xla_sigmoidf(__fadd_rn(giL[t+NH],   ghL[t+NH]));
      float n = xla_tanhf(__fadd_rn(giL[t+2*NH], __fmul_rn(r, ghL[t+2*NH])));
      float hv = hL[t];
      hL[t] = __fadd_rn(__fmul_rn(__fsub_rn(1.0f, z), n), __fmul_rn(z, hv));
    }
    __syncthreads();

    // S3: Hterm = Wa[:,256:384] @ h_new; store 2*(Ht+Ac) (t<128)
    if (t < NH) {
      const float4* war = (const float4*)(Wa + (size_t)t*NH3 + 2*NH);
      const float4* hn4 = (const float4*)hL;
      float acc = 0.f;
      #pragma unroll 8
      for (int k4 = 0; k4 < 32; ++k4) {
        float4 a = war[k4], hv = hn4[k4];
        acc = fmaf(a.x, hv.x, acc); acc = fmaf(a.y, hv.y, acc);
        acc = fmaf(a.z, hv.z, acc); acc = fmaf(a.w, hv.w, acc);
      }
      HtVaP[IDX2(t)].y = __fmul_rn(2.0f, __fadd_rn(acc, AcL[t]));
    }
    __syncthreads();

    // E: attention; 4-fma energy chain, r-accumulate (8 inst/iter)
    float accE = 0.f;
    if (activeS) {
      #pragma unroll 4
      for (int j = 0; j < 64; ++j) {
        float4 af = AF4p[b4 + j];
        float2 hv = HtVaP[b2 + j];
        float e2 = fmaf(af.x, s0r, hv.y);
        e2 = fmaf(af.y, s1r, e2);
        e2 = fmaf(af.z, d0r, e2);
        e2 = fmaf(af.w, d1r, e2);
        float r = __builtin_amdgcn_rcpf(__fadd_rn(__expf(e2), 1.0f));
        accE = fmaf(hv.x, r, accE);
      }
    }
    float accSum = __fadd_rn(accE, __shfl_xor(accE, 1));
    float sc = activeS ? fmaf(-2.0f, accSum, svaR) : 0.f;

    // raw exp + sums butterfly (pair-uniform, xor 2..32)
    float exv = activeS ? __expf(sc) : 0.f;
    {
      float sm = exv;
      float c0 = __fmul_rn(exv, s0r);
      float c1 = __fmul_rn(exv, s1r);
      #pragma unroll
      for (int mm = 2; mm < 64; mm <<= 1) {
        sm = __fadd_rn(sm, __shfl_xor(sm, mm));
        c0 = __fadd_rn(c0, __shfl_xor(c0, mm));
        c1 = __fadd_rn(c1, __shfl_xor(c1, mm));
      }
      if ((t & 63) == 0) { part[w][0] = sm; part[w][1] = c0; part[w][2] = c1; }
    }
    __syncthreads();

    // F: ct2 = 2*(Dc + r0*Cw0 + r1*Cw1 + Cwb) via pre-doubled CW4 (t<128)
    if (t < NH) {
      float sume = part[0][0], r0 = part[0][1], r1 = part[0][2];
      #pragma unroll
      for (int ww = 1; ww < NWAVE; ++ww) {
        sume = __fadd_rn(sume, part[ww][0]);
        r0   = __fadd_rn(r0,   part[ww][1]);
        r1   = __fadd_rn(r1,   part[ww][2]);
      }
      r0 = __fdiv_rn(r0, sume); r1 = __fdiv_rn(r1, sume);
      float4 cw = CW4[t];
      float ct2 = fmaf(r0, cw.x, fmaf(r1, cw.y, cw.z));
      DF4p[IDX4(t)].w = __fadd_rn(cw.w, ct2);
    }
    __syncthreads();

    // G: decoder; 2-fma energy chain, r-accumulate (7 inst/iter, 1 LDS read)
    float accD = 0.f;
    if (activeS) {
      #pragma unroll 4
      for (int j = 0; j < 64; ++j) {
        float4 df = DF4p[b4 + j];
        float d2 = fmaf(df.x, s0r, df.w);
        d2 = fmaf(df.y, s1r, d2);
        float r = __builtin_amdgcn_rcpf(__fadd_rn(__expf(d2), 1.0f));
        accD = fmaf(df.z, r, accD);
      }
    }
    float accDS = __fadd_rn(accD, __shfl_xor(accD, 1));
    float sc2 = activeS ? fmaf(-2.0f, accDS, svdR) : 0.f;

    // decoder raw exp/sum + gumbel argmax (merged butterfly; hoisted gumbel)
    float e2 = activeS ? __expf(sc2) : 0.f;
    if (activeS && (t & 1) == 0) ex2L[s] = e2;
    {
      float gv = -INFINITY;
      int gidx = 1 << 20;
      if (activeS) {
        gv = __fadd_rn(gumL[s], sc2);
        gidx = s;
      }
      float sm = e2;
      #pragma unroll
      for (int mm = 2; mm < 64; mm <<= 1) {
        sm = __fadd_rn(sm, __shfl_xor(sm, mm));
        float ov = __shfl_xor(gv, mm); int oi = __shfl_xor(gidx, mm);
        if (ov > gv || (ov == gv && oi < gidx)) { gv = ov; gidx = oi; }
      }
      if ((t & 63) == 0) { part[w][3] = sm; part[w][4] = gv; partI[w] = gidx; }
    }
    __syncthreads();

    // A: t==0 combines winner, writes outputs + xpL
    if (t == 0) {
      float bv = part[0][4]; int bi = partI[0];
      float sume2 = part[0][3];
      #pragma unroll
      for (int ww = 1; ww < NWAVE; ++ww) {
        float vv = part[ww][4]; int ii = partI[ww];
        if (vv > bv || (vv == bv && ii < bi)) { bv = vv; bi = ii; }
        sume2 = __fadd_rn(sume2, part[ww][3]);
      }
      out[(size_t)b*NS + step] = (float)bi;
      out[(size_t)NB*NS + (size_t)b*NS + step] = __fdiv_rn(ex2L[bi], sume2);
      xpL[0] = st0L[bi]; xpL[1] = st1L[bi];
    }
    __syncthreads();
  }
}

// ---------------- host launch ----------------
extern "C" void kernel_launch(void* const* d_in, const int* in_sizes, int n_in,
                              void* d_out, int out_size, void* d_ws, size_t ws_size,
                              hipStream_t stream) {
  (void)in_sizes; (void)n_in; (void)out_size; (void)d_ws; (void)ws_size;
  const float* stat = (const float*)d_in[0];
  const float* dyn  = (const float*)d_in[1];
  const float* sW   = (const float*)d_in[2];
  const float* sb   = (const float*)d_in[3];
  const float* dW   = (const float*)d_in[4];
  const float* db   = (const float*)d_in[5];
  const float* x0   = (const float*)d_in[6];
  const float* h0   = (const float*)d_in[7];
  const float* Wemb = (const float*)d_in[8];
  const float* bemb = (const float*)d_in[9];
  const float* Wih  = (const float*)d_in[10];
  const float* Whh  = (const float*)d_in[11];
  const float* bih  = (const float*)d_in[12];
  const float* bhh  = (const float*)d_in[13];
  const float* Wa   = (const float*)d_in[14];
  const float* va   = (const float*)d_in[15];
  const float* Wd   = (const float*)d_in[16];
  const float* vd   = (const float*)d_in[17];
  float* out = (float*)d_out;

  k_decode<<<NB, 512, 0, stream>>>(stat, dyn, sW, sb, dW, db, x0, h0,
                                   Wemb, bemb, Wih, Whh, bih, bhh,
                                   Wa, va, Wd, vd, out);
}

// Round 15
// 5486.858 us; speedup vs baseline: 1.2440x; 1.0738x over previous
//
#include <hip/hip_runtime.h>
#include <stdint.h>
#include <math.h>

#define NB 512
#define NS 200
#define NH 128
#define NH3 384
#define NT 1024
#define NWAVE 16

// padded LDS index maps (break half-offset bank aliasing) — validated r9/r10
#define IDX4(h) ((h) + (((h) >> 6) << 2))    // float4: +4 per 64
#define IDX1(h) ((h) + (((h) >> 6) << 4))    // float:  +16 per 64

// ---------------- XLA-exact scalar helpers (GRU gate path only) ----------------
__device__ __forceinline__ float xla_tanhf(float x) {
  float cx = fminf(fmaxf(x, -9.0f), 9.0f);
  float x2 = __fmul_rn(cx, cx);
  float p = -2.76076847742355e-16f;
  p = __fadd_rn(__fmul_rn(x2, p), 2.00018790482477e-13f);
  p = __fadd_rn(__fmul_rn(x2, p), -8.60467152213735e-11f);
  p = __fadd_rn(__fmul_rn(x2, p), 5.12229709037114e-08f);
  p = __fadd_rn(__fmul_rn(x2, p), 1.48572235717979e-05f);
  p = __fadd_rn(__fmul_rn(x2, p), 6.37261928875436e-04f);
  p = __fadd_rn(__fmul_rn(x2, p), 4.89352455891786e-03f);
  p = __fmul_rn(cx, p);
  float q = 1.19825839466702e-06f;
  q = __fadd_rn(__fmul_rn(x2, q), 1.18534705686654e-04f);
  q = __fadd_rn(__fmul_rn(x2, q), 2.26843463243900e-03f);
  q = __fadd_rn(__fmul_rn(x2, q), 4.89352518554385e-03f);
  float r = __fdiv_rn(p, q);
  return (fabsf(x) < 0.0004f) ? x : r;
}

__device__ __forceinline__ float xla_sigmoidf(float x) {
  return __fadd_rn(0.5f, __fmul_rn(0.5f, xla_tanhf(__fmul_rn(0.5f, x))));
}

__device__ __forceinline__ uint32_t rotl32(uint32_t v, int r) {
  return (v << r) | (v >> (32 - r));
}
__device__ __forceinline__ void threefry2x32(uint32_t k0, uint32_t k1,
                                             uint32_t x0, uint32_t x1,
                                             uint32_t& o0, uint32_t& o1) {
  uint32_t k2 = k0 ^ k1 ^ 0x1BD11BDAu;
  x0 += k0; x1 += k1;
  #define TFR(r) { x0 += x1; x1 = rotl32(x1, r); x1 ^= x0; }
  TFR(13) TFR(15) TFR(26) TFR(6)
  x0 += k1; x1 += k2 + 1u;
  TFR(17) TFR(29) TFR(16) TFR(24)
  x0 += k2; x1 += k0 + 2u;
  TFR(13) TFR(15) TFR(26) TFR(6)
  x0 += k0; x1 += k1 + 3u;
  TFR(17) TFR(29) TFR(16) TFR(24)
  x0 += k1; x1 += k2 + 4u;
  TFR(13) TFR(15) TFR(26) TFR(6)
  x0 += k2; x1 += k0 + 5u;
  #undef TFR
  o0 = x0; o1 = x1;
}

__device__ __forceinline__ float bits_to_gumbel(uint32_t bits) {
  const float kTiny = 1.1754943508222875e-38f;
  float f = __fsub_rn(__uint_as_float((bits >> 9) | 0x3F800000u), 1.0f);
  float u = __fadd_rn(__fmul_rn(f, __fsub_rn(1.0f, kTiny)), kTiny);
  u = fmaxf(kTiny, u);
  return -logf(-logf(u));
}

// ---------------- persistent kernel: 2 rows/block, 1024 threads --------------
// waves 0-7: row A = blockIdx.x ; waves 8-15: row B = blockIdx.x + 256
// S1: t<768 -> weight row t loaded ONCE, dots for BOTH rows (halves L2 stream)
__global__ __launch_bounds__(NT, 4) void k_decode(
    const float* __restrict__ stat, const float* __restrict__ dyn,
    const float* __restrict__ sW,   const float* __restrict__ sb,
    const float* __restrict__ dW,   const float* __restrict__ db,
    const float* __restrict__ x0,   const float* __restrict__ h0,
    const float* __restrict__ Wemb, const float* __restrict__ bemb,
    const float* __restrict__ Wih,  const float* __restrict__ Whh,
    const float* __restrict__ bih,  const float* __restrict__ bhh,
    const float* __restrict__ Wa,   const float* __restrict__ va,
    const float* __restrict__ Wd,   const float* __restrict__ vd,
    float* __restrict__ out) {

  __shared__ __align__(16) float st0A[NS], st1A[NS], dy0A[NS], dy1A[NS];
  __shared__ __align__(16) float st0B[NS], st1B[NS], dy0B[NS], dy1B[NS];
  __shared__ float4 AF4p[132];             // {2As0,2As1,2Ad0,2Ad1} padded
  __shared__ float4 DFSp[132];             // {2Ds0,2Ds1,vd,0} padded (shared)
  __shared__ float4 CW4[NH];               // {2Cw0,2Cw1,2Cwb,2Dc}
  __shared__ float  vaP[144];              // va padded
  __shared__ float  Ht2A[144], Ht2B[144];  // 2*(Ht+Ac) per row, padded
  __shared__ float  ct2A[144], ct2B[144];  // 2*(ct+Dc) per row, padded
  __shared__ float  AcL[NH];
  __shared__ float WembL[2*NH], bembL[NH];
  __shared__ float bihL[NH3], bhhL[NH3];
  __shared__ __align__(16) float embA[NH], embB[NH], hA[NH], hB[NH];
  __shared__ float giA[NH3], ghA[NH3], giB[NH3], ghB[NH3];
  __shared__ float ex2A[NS], ex2B[NS], gumA[NS], gumB[NS];
  __shared__ uint32_t keysL[2*NS];
  __shared__ float xpA[2], xpB[2];
  __shared__ float SvL[2];
  __shared__ float part[NWAVE][8];
  __shared__ int   partI[NWAVE];

  const int t = threadIdx.x;
  const int bA = blockIdx.x;
  const int bB = blockIdx.x + 256;
  const int w = t >> 6;                    // global wave 0..15
  const bool rB = (t >= 512);
  const int tr = rB ? (t - 512) : t;       // intra-row lane 0..511
  const int s = tr >> 1;                   // candidate node (lane pairs)
  const int h0i = (tr & 1) * 64;
  const int b4 = h0i + ((h0i >> 6) << 2);
  const int b1 = h0i + ((h0i >> 6) << 4);
  const bool act = (tr < 2*NS);            // 400 task lanes per row

  // ---- one-time setup ----
  if (t < NS) {
    st0A[t] = stat[(size_t)bA*2*NS + t];
    st1A[t] = stat[(size_t)bA*2*NS + NS + t];
    dy0A[t] = dyn[(size_t)bA*2*NS + t];
    dy1A[t] = dyn[(size_t)bA*2*NS + NS + t];
    uint32_t q0, q1;
    threefry2x32(0u, 42u, 0u, (uint32_t)t, q0, q1);
    keysL[2*t] = q0; keysL[2*t + 1] = q1;
  } else if (t >= 256 && t < 256 + NS) {
    int si = t - 256;
    st0B[si] = stat[(size_t)bB*2*NS + si];
    st1B[si] = stat[(size_t)bB*2*NS + NS + si];
    dy0B[si] = dyn[(size_t)bB*2*NS + si];
    dy1B[si] = dyn[(size_t)bB*2*NS + NS + si];
  }
  if (t >= 512 && t < 512 + NH) {
    int h = t - 512;
    const float* war = Wa + (size_t)h * NH3;
    float as0 = 0.f, as1 = 0.f, ad0 = 0.f, ad1 = 0.f, ac = 0.f;
    for (int k = 0; k < NH; ++k) {
      as0 = fmaf(war[k],     sW[k*2+0], as0);
      as1 = fmaf(war[k],     sW[k*2+1], as1);
      ad0 = fmaf(war[NH+k],  dW[k*2+0], ad0);
      ad1 = fmaf(war[NH+k],  dW[k*2+1], ad1);
      ac  = fmaf(war[k],     sb[k],     ac);
    }
    for (int k = 0; k < NH; ++k) ac = fmaf(war[NH+k], db[k], ac);
    AF4p[IDX4(h)] = make_float4(2.f*as0, 2.f*as1, 2.f*ad0, 2.f*ad1);
    vaP[IDX1(h)] = va[h];
    AcL[h] = ac;

    const float* wdr = Wd + (size_t)h * 256;
    float ds0 = 0.f, ds1 = 0.f, dc = 0.f, c0 = 0.f, c1 = 0.f, cb = 0.f;
    for (int k = 0; k < NH; ++k) {
      ds0 = fmaf(wdr[k],    sW[k*2+0], ds0);
      ds1 = fmaf(wdr[k],    sW[k*2+1], ds1);
      dc  = fmaf(wdr[k],    sb[k],     dc);
      c0  = fmaf(wdr[NH+k], sW[k*2+0], c0);
      c1  = fmaf(wdr[NH+k], sW[k*2+1], c1);
      cb  = fmaf(wdr[NH+k], sb[k],     cb);
    }
    DFSp[IDX4(h)] = make_float4(2.f*ds0, 2.f*ds1, vd[h], 0.f);
    CW4[h] = make_float4(2.f*c0, 2.f*c1, 2.f*cb, 2.f*dc);

    bembL[h] = bemb[h];
    WembL[2*h]   = Wemb[2*h];
    WembL[2*h+1] = Wemb[2*h+1];
    hA[h] = h0[h];
    hB[h] = h0[h];
  }
  for (int i = t; i < NH3; i += NT) { bihL[i] = bih[i]; bhhL[i] = bhh[i]; }
  if (t == 0) {
    xpA[0] = x0[0]; xpA[1] = x0[1];
    xpB[0] = x0[0]; xpB[1] = x0[1];
    float sva = 0.f, svd = 0.f;
    for (int h = 0; h < NH; ++h) { sva = __fadd_rn(sva, va[h]); svd = __fadd_rn(svd, vd[h]); }
    SvL[0] = sva; SvL[1] = svd;
  }
  __syncthreads();

  // per-s inputs hoisted (pair-uniform, per row)
  float s0r = 0.f, s1r = 0.f, d0r = 0.f, d1r = 0.f;
  if (act) {
    if (!rB) { s0r = st0A[s]; s1r = st1A[s]; d0r = dy0A[s]; d1r = dy1A[s]; }
    else     { s0r = st0B[s]; s1r = st1B[s]; d0r = dy0B[s]; d1r = dy1B[s]; }
  }
  const float svaR = SvL[0], svdR = SvL[1];
  const float* HtX = rB ? Ht2B : Ht2A;
  const float* ctX = rB ? ct2B : ct2A;
  const float* gumX = rB ? gumB : gumA;

  // ---- 200 decode steps ----
  for (int step = 0; step < NS; ++step) {
    // S0: embA (t<128) | embB ([128,256)) | 400 gumbels ([256,656))
    if (t < NH) {
      float e = fmaf(xpA[1], WembL[t*2+1], __fmul_rn(xpA[0], WembL[t*2+0]));
      embA[t] = __fadd_rn(e, bembL[t]);
    } else if (t < 2*NH) {
      int h = t - NH;
      float e = fmaf(xpB[1], WembL[h*2+1], __fmul_rn(xpB[0], WembL[h*2+0]));
      embB[h] = __fadd_rn(e, bembL[h]);
    } else if (t < 2*NH + 2*NS) {
      int gi = t - 2*NH;                   // 0..399
      uint32_t k0 = keysL[2*step], k1 = keysL[2*step + 1];
      uint32_t q0, q1;
      if (gi < NS) {
        threefry2x32(k0, k1, 0u, (uint32_t)(bA*NS + gi), q0, q1);
        gumA[gi] = bits_to_gumbel(q0 ^ q1);
      } else {
        int si = gi - NS;
        threefry2x32(k0, k1, 0u, (uint32_t)(bB*NS + si), q0, q1);
        gumB[si] = bits_to_gumbel(q0 ^ q1);
      }
    }
    __syncthreads();

    // S1: 768 weight rows, each loaded once, dots for BOTH rows
    // (per-row sequential-k chain bit-identical to r5-r14)
    if (t < 2*NH3) {
      const bool isWih = (t < NH3);
      const float4* wp = isWih
          ? (const float4*)(Wih + (size_t)t * NH)
          : (const float4*)(Whh + (size_t)(t - NH3) * NH);
      const float4* opA = isWih ? (const float4*)embA : (const float4*)hA;
      const float4* opB = isWih ? (const float4*)embB : (const float4*)hB;
      float aA = 0.f, aB = 0.f;
      #pragma unroll 8
      for (int k4 = 0; k4 < 32; ++k4) {
        float4 c = wp[k4];
        float4 vA = opA[k4], vB = opB[k4];
        aA = fmaf(c.x, vA.x, aA); aA = fmaf(c.y, vA.y, aA);
        aA = fmaf(c.z, vA.z, aA); aA = fmaf(c.w, vA.w, aA);
        aB = fmaf(c.x, vB.x, aB); aB = fmaf(c.y, vB.y, aB);
        aB = fmaf(c.z, vB.z, aB); aB = fmaf(c.w, vB.w, aB);
      }
      if (isWih) {
        giA[t] = __fadd_rn(aA, bihL[t]);
        giB[t] = __fadd_rn(aB, bihL[t]);
      } else {
        int row = t - NH3;
        ghA[row] = __fadd_rn(aA, bhhL[row]);
        ghB[row] = __fadd_rn(aB, bhhL[row]);
      }
    }
    __syncthreads();

    // S2: gates (torch r,z,n) EXACT XLA math; rowA t<128, rowB [128,256)
    if (t < NH) {
      float r = xla_sigmoidf(__fadd_rn(giA[t],      ghA[t]));
      float z = xla_sigmoidf(__fadd_rn(giA[t+NH],   ghA[t+NH]));
      float n = xla_tanhf(__fadd_rn(giA[t+2*NH], __fmul_rn(r, ghA[t+2*NH])));
      float hv = hA[t];
      hA[t] = __fadd_rn(__fmul_rn(__fsub_rn(1.0f, z), n), __fmul_rn(z, hv));
    } else if (t < 2*NH) {
      int h = t - NH;
      float r = xla_sigmoidf(__fadd_rn(giB[h],      ghB[h]));
      float z = xla_sigmoidf(__fadd_rn(giB[h+NH],   ghB[h+NH]));
      float n = xla_tanhf(__fadd_rn(giB[h+2*NH], __fmul_rn(r, ghB[h+2*NH])));
      float hv = hB[h];
      hB[h] = __fadd_rn(__fmul_rn(__fsub_rn(1.0f, z), n), __fmul_rn(z, hv));
    }
    __syncthreads();

    // S3: Hterm per row (exact chain); store 2*(Ht+Ac)
    if (t < NH) {
      const float4* war = (const float4*)(Wa + (size_t)t*NH3 + 2*NH);
      const float4* hn4 = (const float4*)hA;
      float acc = 0.f;
      #pragma unroll 8
      for (int k4 = 0; k4 < 32; ++k4) {
        float4 a = war[k4], hv = hn4[k4];
        acc = fmaf(a.x, hv.x, acc); acc = fmaf(a.y, hv.y, acc);
        acc = fmaf(a.z, hv.z, acc); acc = fmaf(a.w, hv.w, acc);
      }
      Ht2A[IDX1(t)] = __fmul_rn(2.0f, __fadd_rn(acc, AcL[t]));
    } else if (t < 2*NH) {
      int h = t - NH;
      const float4* war = (const float4*)(Wa + (size_t)h*NH3 + 2*NH);
      const float4* hn4 = (const float4*)hB;
      float acc = 0.f;
      #pragma unroll 8
      for (int k4 = 0; k4 < 32; ++k4) {
        float4 a = war[k4], hv = hn4[k4];
        acc = fmaf(a.x, hv.x, acc); acc = fmaf(a.y, hv.y, acc);
        acc = fmaf(a.z, hv.z, acc); acc = fmaf(a.w, hv.w, acc);
      }
      Ht2B[IDX1(h)] = __fmul_rn(2.0f, __fadd_rn(acc, AcL[h]));
    }
    __syncthreads();

    // E: attention; 4-fma energy, r-accumulate (r14 numerics, per row)
    float accE = 0.f;
    if (act) {
      #pragma unroll 4
      for (int j = 0; j < 64; ++j) {
        float4 af = AF4p[b4 + j];
        float e2 = fmaf(af.x, s0r, HtX[b1 + j]);
        e2 = fmaf(af.y, s1r, e2);
        e2 = fmaf(af.z, d0r, e2);
        e2 = fmaf(af.w, d1r, e2);
        float r = __builtin_amdgcn_rcpf(__fadd_rn(__expf(e2), 1.0f));
        accE = fmaf(vaP[b1 + j], r, accE);
      }
    }
    float accSum = __fadd_rn(accE, __shfl_xor(accE, 1));
    float sc = act ? fmaf(-2.0f, accSum, svaR) : 0.f;

    float exv = act ? __expf(sc) : 0.f;
    {
      float sm = exv;
      float c0 = __fmul_rn(exv, s0r);
      float c1 = __fmul_rn(exv, s1r);
      #pragma unroll
      for (int mm = 2; mm < 64; mm <<= 1) {
        sm = __fadd_rn(sm, __shfl_xor(sm, mm));
        c0 = __fadd_rn(c0, __shfl_xor(c0, mm));
        c1 = __fadd_rn(c1, __shfl_xor(c1, mm));
      }
      if ((t & 63) == 0) { part[w][0] = sm; part[w][1] = c0; part[w][2] = c1; }
    }
    __syncthreads();

    // F: ct2 per row; rowA from part[0..7], rowB from part[8..15]
    if (t < 2*NH) {
      int h = t & (NH - 1);
      int base = (t < NH) ? 0 : 8;
      float sume = part[base][0], r0 = part[base][1], r1 = part[base][2];
      #pragma unroll
      for (int ww = 1; ww < 8; ++ww) {
        sume = __fadd_rn(sume, part[base + ww][0]);
        r0   = __fadd_rn(r0,   part[base + ww][1]);
        r1   = __fadd_rn(r1,   part[base + ww][2]);
      }
      r0 = __fdiv_rn(r0, sume); r1 = __fdiv_rn(r1, sume);
      float4 cw = CW4[h];
      float ct2 = fmaf(r0, cw.x, fmaf(r1, cw.y, cw.z));
      if (t < NH) ct2A[IDX1(h)] = __fadd_rn(cw.w, ct2);
      else        ct2B[IDX1(h)] = __fadd_rn(cw.w, ct2);
    }
    __syncthreads();

    // G: decoder; 2-fma energy, r-accumulate; hoisted gumbel
    float accD = 0.f;
    if (act) {
      #pragma unroll 4
      for (int j = 0; j < 64; ++j) {
        float4 df = DFSp[b4 + j];
        float d2 = fmaf(df.x, s0r, ctX[b1 + j]);
        d2 = fmaf(df.y, s1r, d2);
        float r = __builtin_amdgcn_rcpf(__fadd_rn(__expf(d2), 1.0f));
        accD = fmaf(df.z, r, accD);
      }
    }
    float accDS = __fadd_rn(accD, __shfl_xor(accD, 1));
    float sc2 = act ? fmaf(-2.0f, accDS, svdR) : 0.f;

    float e2v = act ? __expf(sc2) : 0.f;
    if (act && (tr & 1) == 0) { if (!rB) ex2A[s] = e2v; else ex2B[s] = e2v; }
    {
      float gv = -INFINITY;
      int gidx = 1 << 20;
      if (act) {
        gv = __fadd_rn(gumX[s], sc2);
        gidx = s;
      }
      float sm = e2v;
      #pragma unroll
      for (int mm = 2; mm < 64; mm <<= 1) {
        sm = __fadd_rn(sm, __shfl_xor(sm, mm));
        float ov = __shfl_xor(gv, mm); int oi = __shfl_xor(gidx, mm);
        if (ov > gv || (ov == gv && oi < gidx)) { gv = ov; gidx = oi; }
      }
      if ((t & 63) == 0) { part[w][3] = sm; part[w][4] = gv; partI[w] = gidx; }
    }
    __syncthreads();

    // A: winner per row; t==0 rowA, t==512 rowB
    if (t == 0) {
      float bv = part[0][4]; int bi = partI[0];
      float sume2 = part[0][3];
      #pragma unroll
      for (int ww = 1; ww < 8; ++ww) {
        float vv = part[ww][4]; int ii = partI[ww];
        if (vv > bv || (vv == bv && ii < bi)) { bv = vv; bi = ii; }
        sume2 = __fadd_rn(sume2, part[ww][3]);
      }
      out[(size_t)bA*NS + step] = (float)bi;
      out[(size_t)NB*NS + (size_t)bA*NS + step] = __fdiv_rn(ex2A[bi], sume2);
      xpA[0] = st0A[bi]; xpA[1] = st1A[bi];
    } else if (t == 512) {
      float bv = part[8][4]; int bi = partI[8];
      float sume2 = part[8][3];
      #pragma unroll
      for (int ww = 9; ww < 16; ++ww) {
        float vv = part[ww][4]; int ii = partI[ww];
        if (vv > bv || (vv == bv && ii < bi)) { bv = vv; bi = ii; }
        sume2 = __fadd_rn(sume2, part[ww][3]);
      }
      out[(size_t)bB*NS + step] = (float)bi;
      out[(size_t)NB*NS + (size_t)bB*NS + step] = __fdiv_rn(ex2B[bi], sume2);
      xpB[0] = st0B[bi]; xpB[1] = st1B[bi];
    }
    __syncthreads();
  }
}

// ---------------- host launch ----------------
extern "C" void kernel_launch(void* const* d_in, const int* in_sizes, int n_in,
                              void* d_out, int out_size, void* d_ws, size_t ws_size,
                              hipStream_t stream) {
  (void)in_sizes; (void)n_in; (void)out_size; (void)d_ws; (void)ws_size;
  const float* stat = (const float*)d_in[0];
  const float* dyn  = (const float*)d_in[1];
  const float* sW   = (const float*)d_in[2];
  const float* sb   = (const float*)d_in[3];
  const float* dW   = (const float*)d_in[4];
  const float* db   = (const float*)d_in[5];
  const float* x0   = (const float*)d_in[6];
  const float* h0   = (const float*)d_in[7];
  const float* Wemb = (const float*)d_in[8];
  const float* bemb = (const float*)d_in[9];
  const float* Wih  = (const float*)d_in[10];
  const float* Whh  = (const float*)d_in[11];
  const float* bih  = (const float*)d_in[12];
  const float* bhh  = (const float*)d_in[13];
  const float* Wa   = (const float*)d_in[14];
  const float* va   = (const float*)d_in[15];
  const float* Wd   = (const float*)d_in[16];
  const float* vd   = (const float*)d_in[17];
  float* out = (float*)d_out;

  k_decode<<<NB/2, NT, 0, stream>>>(stat, dyn, sW, sb, dW, db, x0, h0,
                                    Wemb, bemb, Wih, Whh, bih, bhh,
                                    Wa, va, Wd, vd, out);
}